// Round 1
// baseline (1254.264 us; speedup 1.0000x reference)
//
#include <hip/hip_runtime.h>

// Problem constants (from reference): B=64, N=2048, DIM_IN=DIM_OUT=64, CHEB_K=3, EMBED_DIM=10
#define NN 2048
#define BB 64
#define CC 64
#define ED 10
#define KK 3

// ---------------------------------------------------------------------------
// Kernel 1: A = softmax(relu(E E^T), axis=1).  One block per row n.
// ---------------------------------------------------------------------------
__global__ __launch_bounds__(256) void supports_kernel(const float* __restrict__ E,
                                                       float* __restrict__ A) {
    const int n = blockIdx.x;
    const int tid = threadIdx.x;

    float en[ED];
#pragma unroll
    for (int d = 0; d < ED; ++d) en[d] = E[n * ED + d];

    float sv[NN / 256];
    float lmax = 0.0f;  // relu outputs are >= 0, so 0 is a safe init
#pragma unroll
    for (int j = 0; j < NN / 256; ++j) {
        const int m = tid + j * 256;
        const float* Em = E + m * ED;
        float dot = 0.0f;
#pragma unroll
        for (int d = 0; d < ED; ++d) dot += en[d] * Em[d];
        float s = fmaxf(dot, 0.0f);
        sv[j] = s;
        lmax = fmaxf(lmax, s);
    }

    __shared__ float smax[4];
    __shared__ float ssum[4];

    // wave reduce (wave = 64 lanes), then cross-wave via LDS
#pragma unroll
    for (int off = 32; off > 0; off >>= 1) lmax = fmaxf(lmax, __shfl_down(lmax, off, 64));
    if ((tid & 63) == 0) smax[tid >> 6] = lmax;
    __syncthreads();
    const float bmax = fmaxf(fmaxf(smax[0], smax[1]), fmaxf(smax[2], smax[3]));

    float lsum = 0.0f;
#pragma unroll
    for (int j = 0; j < NN / 256; ++j) {
        sv[j] = __expf(sv[j] - bmax);
        lsum += sv[j];
    }
#pragma unroll
    for (int off = 32; off > 0; off >>= 1) lsum += __shfl_down(lsum, off, 64);
    if ((tid & 63) == 0) ssum[tid >> 6] = lsum;
    __syncthreads();
    const float inv = 1.0f / (ssum[0] + ssum[1] + ssum[2] + ssum[3]);

#pragma unroll
    for (int j = 0; j < NN / 256; ++j) {
        A[(size_t)n * NN + tid + j * 256] = sv[j] * inv;
    }
}

// ---------------------------------------------------------------------------
// Kernel 2: per-batch Y_b = alpha * (A @ X_b) + beta * Z_b
//   A: [N,N], X_b/Z_b/Y_b: [N, C] slices of [B,N,C].
//   grid = (N/64, B), block = 256. 64x64 LDS tiles, 4x4 register tile/thread.
// ---------------------------------------------------------------------------
__global__ __launch_bounds__(256) void spmm_kernel(const float* __restrict__ A,
                                                   const float* __restrict__ X,
                                                   const float* __restrict__ Z,
                                                   float* __restrict__ Y,
                                                   float alpha, float beta) {
    const int b = blockIdx.y;
    const int n0 = blockIdx.x * 64;
    const float* Xb = X + (size_t)b * NN * CC;
    float* Yb = Y + (size_t)b * NN * CC;

    // pad to 68 floats: rows stay 16B-aligned for float4, banks decorrelate
    __shared__ float As[64][68];  // As[i][kk] = A[n0+i][m0+kk]
    __shared__ float Xs[64][68];  // Xs[kk][c] = X_b[m0+kk][c]

    const int tid = threadIdx.x;
    const int ti = tid >> 4;  // 0..15 (row group)
    const int tj = tid & 15;  // 0..15 (col group)

    float acc[4][4];
#pragma unroll
    for (int i = 0; i < 4; ++i)
#pragma unroll
        for (int j = 0; j < 4; ++j) acc[i][j] = 0.0f;

    for (int m0 = 0; m0 < NN; m0 += 64) {
        // stage 64x64 tiles of A and X_b, float4 per slot (1024 slots, 4/thread)
#pragma unroll
        for (int l = 0; l < 4; ++l) {
            const int idx = tid + l * 256;
            const int row = idx >> 4;
            const int col = (idx & 15) << 2;
            const float4 av = *(const float4*)(A + (size_t)(n0 + row) * NN + m0 + col);
            *(float4*)&As[row][col] = av;
            const float4 xv = *(const float4*)(Xb + (size_t)(m0 + row) * CC + col);
            *(float4*)&Xs[row][col] = xv;
        }
        __syncthreads();

#pragma unroll
        for (int kk = 0; kk < 64; ++kk) {
            float a[4], xr[4];
#pragma unroll
            for (int i = 0; i < 4; ++i) a[i] = As[ti + 16 * i][kk];
#pragma unroll
            for (int j = 0; j < 4; ++j) xr[j] = Xs[kk][tj + 16 * j];
#pragma unroll
            for (int i = 0; i < 4; ++i)
#pragma unroll
                for (int j = 0; j < 4; ++j) acc[i][j] += a[i] * xr[j];
        }
        __syncthreads();
    }

#pragma unroll
    for (int i = 0; i < 4; ++i) {
        const int r = n0 + ti + 16 * i;
#pragma unroll
        for (int j = 0; j < 4; ++j) {
            const int c = tj + 16 * j;
            float v = alpha * acc[i][j];
            if (beta != 0.0f) v += beta * Z[(size_t)b * NN * CC + (size_t)r * CC + c];
            Yb[(size_t)r * CC + c] = v;
        }
    }
}

// ---------------------------------------------------------------------------
// Kernel 3: fused epilogue. One block per node n.
//   W_n[k,i,o] = sum_d E[n,d] * Wp[d,k,i,o]   (synthesized per k in LDS)
//   bias_n[o]  = sum_d E[n,d] * bp[d,o]
//   out[b,n,o] = bias_n[o] + sum_k sum_i xg_k[b,n,i] * W_n[k,i,o]
//   with xg_0 = x, xg_1 = y1, xg_2 = y2.
// ---------------------------------------------------------------------------
__global__ __launch_bounds__(256) void out_kernel(const float* __restrict__ E,
                                                  const float* __restrict__ Wp,
                                                  const float* __restrict__ bp,
                                                  const float* __restrict__ x,
                                                  const float* __restrict__ y1,
                                                  const float* __restrict__ y2,
                                                  float* __restrict__ out) {
    const int n = blockIdx.x;
    const int tid = threadIdx.x;

    __shared__ float w[CC * CC];       // 16 KB: W_n[k] for current k
    __shared__ float xg[BB][CC + 4];   // 17.4 KB: xg_k rows for all 64 batches
    __shared__ float en_s[ED];
    __shared__ float bias_s[CC];

    if (tid < ED) en_s[tid] = E[n * ED + tid];
    __syncthreads();
    float en[ED];
#pragma unroll
    for (int d = 0; d < ED; ++d) en[d] = en_s[d];

    if (tid < CC) {
        float bsum = 0.0f;
#pragma unroll
        for (int d = 0; d < ED; ++d) bsum += en[d] * bp[d * CC + tid];
        bias_s[tid] = bsum;
    }

    const int ot4 = (tid & 15) << 2;  // o base: 0,4,...,60
    const int bt = tid >> 4;          // 0..15 (batch group)

    float acc[4][4];
#pragma unroll
    for (int jb = 0; jb < 4; ++jb)
#pragma unroll
        for (int jo = 0; jo < 4; ++jo) acc[jb][jo] = 0.0f;

    for (int k = 0; k < KK; ++k) {
        const float* src = (k == 0) ? x : (k == 1) ? y1 : y2;
        __syncthreads();  // protect LDS from previous iteration's readers
        // stage xg_k rows (64 b x 64 i), float4
        for (int idx = tid; idx < BB * CC / 4; idx += 256) {
            const int b = idx >> 4;
            const int c = (idx & 15) << 2;
            *(float4*)&xg[b][c] = *(const float4*)(src + ((size_t)b * NN + n) * CC + c);
        }
        // synthesize W_n[k] (64x64)
        for (int idx = tid; idx < CC * CC; idx += 256) {
            float s = 0.0f;
#pragma unroll
            for (int d = 0; d < ED; ++d) s += en[d] * Wp[(size_t)(d * KK + k) * CC * CC + idx];
            w[idx] = s;
        }
        __syncthreads();

#pragma unroll
        for (int i = 0; i < CC; ++i) {
            const float4 wv = *(const float4*)&w[i * CC + ot4];
            float xv[4];
#pragma unroll
            for (int jb = 0; jb < 4; ++jb) xv[jb] = xg[bt + 16 * jb][i];
#pragma unroll
            for (int jb = 0; jb < 4; ++jb) {
                acc[jb][0] += xv[jb] * wv.x;
                acc[jb][1] += xv[jb] * wv.y;
                acc[jb][2] += xv[jb] * wv.z;
                acc[jb][3] += xv[jb] * wv.w;
            }
        }
    }
    __syncthreads();

#pragma unroll
    for (int jb = 0; jb < 4; ++jb) {
        const int b = bt + 16 * jb;
        float4 v;
        v.x = acc[jb][0] + bias_s[ot4 + 0];
        v.y = acc[jb][1] + bias_s[ot4 + 1];
        v.z = acc[jb][2] + bias_s[ot4 + 2];
        v.w = acc[jb][3] + bias_s[ot4 + 3];
        *(float4*)(out + ((size_t)b * NN + n) * CC + ot4) = v;
    }
}

// ---------------------------------------------------------------------------
// Host launch: A = softmax(relu(EE^T)); y1 = A@x; y2 = 2*A@y1 - x; fused out.
// Workspace: A (16 MB) + y1 (32 MB) + y2 (32 MB) = 80 MB fp32.
// ---------------------------------------------------------------------------
extern "C" void kernel_launch(void* const* d_in, const int* in_sizes, int n_in,
                              void* d_out, int out_size, void* d_ws, size_t ws_size,
                              hipStream_t stream) {
    const float* x  = (const float*)d_in[0];
    const float* E  = (const float*)d_in[1];
    const float* Wp = (const float*)d_in[2];
    const float* bp = (const float*)d_in[3];
    // d_in[4] is cheb_k == 3 (hardcoded)

    float* A  = (float*)d_ws;
    float* y1 = A + (size_t)NN * NN;
    float* y2 = y1 + (size_t)BB * NN * CC;
    float* out = (float*)d_out;

    supports_kernel<<<NN, 256, 0, stream>>>(E, A);
    spmm_kernel<<<dim3(NN / 64, BB), 256, 0, stream>>>(A, x, x, y1, 1.0f, 0.0f);
    spmm_kernel<<<dim3(NN / 64, BB), 256, 0, stream>>>(A, y1, x, y2, 2.0f, -1.0f);
    out_kernel<<<NN, 256, 0, stream>>>(E, Wp, bp, x, y1, y2, out);
}

// Round 2
// 356.413 us; speedup vs baseline: 3.5191x; 3.5191x over previous
//
#include <hip/hip_runtime.h>

// B=64, N=2048, DIM_IN=DIM_OUT=64, CHEB_K=3, EMBED_DIM=10
#define NN 2048
#define BB 64
#define CC 64
#define ED 10
#define KK 3
#define JJ (BB * CC)  // 4096

typedef unsigned short ushort_t;
typedef __attribute__((ext_vector_type(8))) short short8;   // 8 bf16 = 4 VGPRs
typedef __attribute__((ext_vector_type(4))) float f32x4;

static __device__ __forceinline__ ushort_t f2bf(float f) {
    union { float f; unsigned u; } x{f};
    unsigned r = x.u + 0x7FFF + ((x.u >> 16) & 1);  // RTN-even
    return (ushort_t)(r >> 16);
}
static __device__ __forceinline__ float bf2f(ushort_t h) {
    union { unsigned u; float f; } x;
    x.u = ((unsigned)h) << 16;
    return x.f;
}

// ---------------------------------------------------------------------------
// Kernel 1: A_bf16[n][m] = softmax(relu(E E^T), axis=1). One block per row n.
// ---------------------------------------------------------------------------
__global__ __launch_bounds__(256) void supports_kernel(const float* __restrict__ E,
                                                       ushort_t* __restrict__ Ab) {
    const int n = blockIdx.x;
    const int tid = threadIdx.x;

    float en[ED];
#pragma unroll
    for (int d = 0; d < ED; ++d) en[d] = E[n * ED + d];

    float sv[NN / 256];
    float lmax = 0.0f;  // relu >= 0
#pragma unroll
    for (int j = 0; j < NN / 256; ++j) {
        const int m = tid + j * 256;
        const float* Em = E + m * ED;
        float dot = 0.0f;
#pragma unroll
        for (int d = 0; d < ED; ++d) dot += en[d] * Em[d];
        float s = fmaxf(dot, 0.0f);
        sv[j] = s;
        lmax = fmaxf(lmax, s);
    }

    __shared__ float smax[4];
    __shared__ float ssum[4];
#pragma unroll
    for (int off = 32; off > 0; off >>= 1) lmax = fmaxf(lmax, __shfl_down(lmax, off, 64));
    if ((tid & 63) == 0) smax[tid >> 6] = lmax;
    __syncthreads();
    const float bmax = fmaxf(fmaxf(smax[0], smax[1]), fmaxf(smax[2], smax[3]));

    float lsum = 0.0f;
#pragma unroll
    for (int j = 0; j < NN / 256; ++j) {
        sv[j] = __expf(sv[j] - bmax);
        lsum += sv[j];
    }
#pragma unroll
    for (int off = 32; off > 0; off >>= 1) lsum += __shfl_down(lsum, off, 64);
    if ((tid & 63) == 0) ssum[tid >> 6] = lsum;
    __syncthreads();
    const float inv = 1.0f / (ssum[0] + ssum[1] + ssum[2] + ssum[3]);

#pragma unroll
    for (int j = 0; j < NN / 256; ++j) {
        Ab[(size_t)n * NN + tid + j * 256] = f2bf(sv[j] * inv);
    }
}

// ---------------------------------------------------------------------------
// Kernel 2: transpose x[b][n][c] fp32 -> xT[(b*64+c)][n] bf16.
// grid (N/64, B), block 256. 64x64 tile via LDS.
// ---------------------------------------------------------------------------
__global__ __launch_bounds__(256) void transpose_kernel(const float* __restrict__ x,
                                                        ushort_t* __restrict__ xT) {
    const int n0 = blockIdx.x * 64;
    const int b = blockIdx.y;
    const int tid = threadIdx.x;

    __shared__ float tb[64][68];  // tb[c][nn]

    // read: 64 nn x 64 c floats, float4 along c
#pragma unroll
    for (int l = 0; l < 4; ++l) {
        const int idx = tid + l * 256;
        const int nn = idx >> 4;
        const int c4 = (idx & 15) << 2;
        const float4 v = *(const float4*)(x + ((size_t)b * NN + n0 + nn) * CC + c4);
        tb[c4 + 0][nn] = v.x;
        tb[c4 + 1][nn] = v.y;
        tb[c4 + 2][nn] = v.z;
        tb[c4 + 3][nn] = v.w;
    }
    __syncthreads();

    // write: row (b*64+c), 64 bf16 contiguous in n
#pragma unroll
    for (int l = 0; l < 2; ++l) {
        const int idx = tid + l * 256;  // 0..511 : 64 rows x 8 chunks
        const int c = idx >> 3;
        const int ch = (idx & 7) << 3;  // element base (8 bf16 = 16 B)
        ushort_t pack[8];
#pragma unroll
        for (int e = 0; e < 8; ++e) pack[e] = f2bf(tb[c][ch + e]);
        *(float4*)(xT + (size_t)(b * 64 + c) * NN + n0 + ch) = *(float4*)pack;
    }
}

// ---------------------------------------------------------------------------
// Kernel 3: NT-GEMM on matrix cores.
//   Ct[j][m] = alpha * sum_k A[m][k]*Bt[j][k]  (+ beta * Zt[j][m])
//   A: [2048 x 2048] bf16 (K-major rows), Bt: [4096 x 2048] bf16 (K-major rows)
//   Ct/Zt: [4096 x 2048] bf16.
//   128x128 tile, BK=64, 4 waves each 64x64 via 4x4 mfma_f32_16x16x32_bf16.
// ---------------------------------------------------------------------------
template <bool HASZ>
__global__ __launch_bounds__(256) void gemm_nt(const ushort_t* __restrict__ A,
                                               const ushort_t* __restrict__ Bt,
                                               const ushort_t* __restrict__ Zt,
                                               ushort_t* __restrict__ Ct,
                                               float alpha, float beta) {
    const int j0 = blockIdx.x * 128;
    const int m0 = blockIdx.y * 128;
    const int tid = threadIdx.x;
    const int lane = tid & 63;
    const int l16 = lane & 15;
    const int quad = lane >> 4;
    const int w = tid >> 6;      // wave 0..3
    const int wm = (w >> 1) * 64;
    const int wj = (w & 1) * 64;

#define LDP 72  // padded row stride (bf16 elems): 144 B -> bank-balanced b128
    __shared__ ushort_t As[128 * LDP];
    __shared__ ushort_t Bs[128 * LDP];

    f32x4 acc[4][4];
#pragma unroll
    for (int mi = 0; mi < 4; ++mi)
#pragma unroll
        for (int ji = 0; ji < 4; ++ji) acc[mi][ji] = (f32x4){0.f, 0.f, 0.f, 0.f};

    for (int k0 = 0; k0 < NN; k0 += 64) {
        // stage 128x64 bf16 tiles of A and Bt (16 B per slot, 1024 slots each)
#pragma unroll
        for (int l = 0; l < 4; ++l) {
            const int idx = tid + l * 256;
            const int row = idx >> 3;
            const int c16 = (idx & 7) << 3;  // k element base
            *(float4*)&As[row * LDP + c16] =
                *(const float4*)(A + (size_t)(m0 + row) * NN + k0 + c16);
            *(float4*)&Bs[row * LDP + c16] =
                *(const float4*)(Bt + (size_t)(j0 + row) * NN + k0 + c16);
        }
        __syncthreads();

#pragma unroll
        for (int ks = 0; ks < 64; ks += 32) {
            short8 av[4], bv[4];
#pragma unroll
            for (int mi = 0; mi < 4; ++mi)
                av[mi] = *(const short8*)&As[(wm + mi * 16 + l16) * LDP + ks + quad * 8];
#pragma unroll
            for (int ji = 0; ji < 4; ++ji)
                bv[ji] = *(const short8*)&Bs[(wj + ji * 16 + l16) * LDP + ks + quad * 8];
#pragma unroll
            for (int mi = 0; mi < 4; ++mi)
#pragma unroll
                for (int ji = 0; ji < 4; ++ji)
                    acc[mi][ji] = __builtin_amdgcn_mfma_f32_16x16x32_bf16(
                        av[mi], bv[ji], acc[mi][ji], 0, 0, 0);
        }
        __syncthreads();
    }

    // C/D layout (16x16x32): col = lane&15 (j side), row = quad*4 + reg (m side).
    // Write transposed: Ct[j][m] -> reg runs along m => 4 contiguous bf16 (8 B).
#pragma unroll
    for (int mi = 0; mi < 4; ++mi) {
#pragma unroll
        for (int ji = 0; ji < 4; ++ji) {
            const int j = j0 + wj + ji * 16 + l16;
            const int m = m0 + wm + mi * 16 + quad * 4;
            float v[4];
#pragma unroll
            for (int r = 0; r < 4; ++r) v[r] = alpha * acc[mi][ji][r];
            if (HASZ) {
                ushort_t z[4];
                *(unsigned long long*)z = *(const unsigned long long*)(Zt + (size_t)j * NN + m);
#pragma unroll
                for (int r = 0; r < 4; ++r) v[r] += beta * bf2f(z[r]);
            }
            ushort_t o[4];
#pragma unroll
            for (int r = 0; r < 4; ++r) o[r] = f2bf(v[r]);
            *(unsigned long long*)(Ct + (size_t)j * NN + m) = *(unsigned long long*)o;
        }
    }
#undef LDP
}

// ---------------------------------------------------------------------------
// Kernel 4: fused epilogue. One block per node n.
//   W_n[k,i,o] = sum_d E[n,d]*Wp[d,k,i,o]; bias_n[o] = sum_d E[n,d]*bp[d,o]
//   out[b,n,o] = bias_n[o] + sum_k sum_i xgT_k[(b*64+i)][n] * W_n[k,i,o]
//   sources (bf16, [j][n] layout): xT, y1T, y2T.
// ---------------------------------------------------------------------------
__global__ __launch_bounds__(256) void out_kernel(const float* __restrict__ E,
                                                  const float* __restrict__ Wp,
                                                  const float* __restrict__ bp,
                                                  const ushort_t* __restrict__ xT,
                                                  const ushort_t* __restrict__ y1T,
                                                  const ushort_t* __restrict__ y2T,
                                                  float* __restrict__ out) {
    const int n = blockIdx.x;
    const int tid = threadIdx.x;

    __shared__ float w[CC * CC];          // 16 KB
    __shared__ ushort_t xg[BB * 72];      // 9 KB, padded stride 72
    __shared__ float en_s[ED];
    __shared__ float bias_s[CC];

    if (tid < ED) en_s[tid] = E[n * ED + tid];
    __syncthreads();
    float en[ED];
#pragma unroll
    for (int d = 0; d < ED; ++d) en[d] = en_s[d];

    if (tid < CC) {
        float bsum = 0.0f;
#pragma unroll
        for (int d = 0; d < ED; ++d) bsum += en[d] * bp[d * CC + tid];
        bias_s[tid] = bsum;
    }

    const int ot4 = (tid & 15) << 2;  // o base
    const int bt = tid >> 4;          // 0..15

    float acc[4][4];
#pragma unroll
    for (int jb = 0; jb < 4; ++jb)
#pragma unroll
        for (int jo = 0; jo < 4; ++jo) acc[jb][jo] = 0.0f;

    for (int k = 0; k < KK; ++k) {
        const ushort_t* src = (k == 0) ? xT : (k == 1) ? y1T : y2T;
        __syncthreads();
        // stage column n of src: 4096 bf16, strided gather
        for (int idx = tid; idx < BB * CC; idx += 256) {
            xg[(idx >> 6) * 72 + (idx & 63)] = src[(size_t)idx * NN + n];
        }
        // synthesize W_n[k]
        for (int idx = tid; idx < CC * CC; idx += 256) {
            float s = 0.0f;
#pragma unroll
            for (int d = 0; d < ED; ++d) s += en[d] * Wp[(size_t)(d * KK + k) * CC * CC + idx];
            w[idx] = s;
        }
        __syncthreads();

#pragma unroll
        for (int i = 0; i < CC; ++i) {
            const float4 wv = *(const float4*)&w[i * CC + ot4];
            float xv[4];
#pragma unroll
            for (int jb = 0; jb < 4; ++jb) xv[jb] = bf2f(xg[(bt + 16 * jb) * 72 + i]);
#pragma unroll
            for (int jb = 0; jb < 4; ++jb) {
                acc[jb][0] += xv[jb] * wv.x;
                acc[jb][1] += xv[jb] * wv.y;
                acc[jb][2] += xv[jb] * wv.z;
                acc[jb][3] += xv[jb] * wv.w;
            }
        }
    }
    __syncthreads();

#pragma unroll
    for (int jb = 0; jb < 4; ++jb) {
        const int b = bt + 16 * jb;
        float4 v;
        v.x = acc[jb][0] + bias_s[ot4 + 0];
        v.y = acc[jb][1] + bias_s[ot4 + 1];
        v.z = acc[jb][2] + bias_s[ot4 + 2];
        v.w = acc[jb][3] + bias_s[ot4 + 3];
        *(float4*)(out + ((size_t)b * NN + n) * CC + ot4) = v;
    }
}

// ---------------------------------------------------------------------------
// Host launch.
// Workspace (bf16): A_bf 8 MB | xT 16 MB | y1T 16 MB | y2T 16 MB = 56 MB.
// ---------------------------------------------------------------------------
extern "C" void kernel_launch(void* const* d_in, const int* in_sizes, int n_in,
                              void* d_out, int out_size, void* d_ws, size_t ws_size,
                              hipStream_t stream) {
    const float* x  = (const float*)d_in[0];
    const float* E  = (const float*)d_in[1];
    const float* Wp = (const float*)d_in[2];
    const float* bp = (const float*)d_in[3];

    ushort_t* Ab  = (ushort_t*)d_ws;                    // [2048][2048]
    ushort_t* xT  = Ab + (size_t)NN * NN;               // [4096][2048]
    ushort_t* y1T = xT + (size_t)JJ * NN;               // [4096][2048]
    ushort_t* y2T = y1T + (size_t)JJ * NN;              // [4096][2048]
    float* out = (float*)d_out;

    supports_kernel<<<NN, 256, 0, stream>>>(E, Ab);
    transpose_kernel<<<dim3(NN / 64, BB), 256, 0, stream>>>(x, xT);
    // y1T = (A @ x)^T
    gemm_nt<false><<<dim3(JJ / 128, NN / 128), 256, 0, stream>>>(Ab, xT, nullptr, y1T, 1.0f, 0.0f);
    // y2T = (2 A @ y1)^T - xT
    gemm_nt<true><<<dim3(JJ / 128, NN / 128), 256, 0, stream>>>(Ab, y1T, xT, y2T, 2.0f, -1.0f);
    out_kernel<<<NN, 256, 0, stream>>>(E, Wp, bp, xT, y1T, y2T, out);
}

// Round 3
// 271.476 us; speedup vs baseline: 4.6202x; 1.3129x over previous
//
#include <hip/hip_runtime.h>

// B=64, N=2048, DIM_IN=DIM_OUT=64, CHEB_K=3, EMBED_DIM=10
#define NN 2048
#define BB 64
#define CC 64
#define ED 10
#define KK 3
#define JJ (BB * CC)  // 4096

typedef unsigned short ushort_t;
typedef __attribute__((ext_vector_type(8))) short short8;   // 8 bf16 = 4 VGPRs
typedef __attribute__((ext_vector_type(4))) float f32x4;

static __device__ __forceinline__ ushort_t f2bf(float f) {
    union { float f; unsigned u; } x{f};
    unsigned r = x.u + 0x7FFF + ((x.u >> 16) & 1);  // RTN-even
    return (ushort_t)(r >> 16);
}
static __device__ __forceinline__ float bf2f(ushort_t h) {
    union { unsigned u; float f; } x;
    x.u = ((unsigned)h) << 16;
    return x.f;
}

// ---------------------------------------------------------------------------
// Kernel 1: A_bf16[n][m] = softmax(relu(E E^T), axis=1). One block per row n.
// ---------------------------------------------------------------------------
__global__ __launch_bounds__(256) void supports_kernel(const float* __restrict__ E,
                                                       ushort_t* __restrict__ Ab) {
    const int n = blockIdx.x;
    const int tid = threadIdx.x;

    float en[ED];
#pragma unroll
    for (int d = 0; d < ED; ++d) en[d] = E[n * ED + d];

    float sv[NN / 256];
    float lmax = 0.0f;  // relu >= 0
#pragma unroll
    for (int j = 0; j < NN / 256; ++j) {
        const int m = tid + j * 256;
        const float* Em = E + m * ED;
        float dot = 0.0f;
#pragma unroll
        for (int d = 0; d < ED; ++d) dot += en[d] * Em[d];
        float s = fmaxf(dot, 0.0f);
        sv[j] = s;
        lmax = fmaxf(lmax, s);
    }

    __shared__ float smax[4];
    __shared__ float ssum[4];
#pragma unroll
    for (int off = 32; off > 0; off >>= 1) lmax = fmaxf(lmax, __shfl_down(lmax, off, 64));
    if ((tid & 63) == 0) smax[tid >> 6] = lmax;
    __syncthreads();
    const float bmax = fmaxf(fmaxf(smax[0], smax[1]), fmaxf(smax[2], smax[3]));

    float lsum = 0.0f;
#pragma unroll
    for (int j = 0; j < NN / 256; ++j) {
        sv[j] = __expf(sv[j] - bmax);
        lsum += sv[j];
    }
#pragma unroll
    for (int off = 32; off > 0; off >>= 1) lsum += __shfl_down(lsum, off, 64);
    if ((tid & 63) == 0) ssum[tid >> 6] = lsum;
    __syncthreads();
    const float inv = 1.0f / (ssum[0] + ssum[1] + ssum[2] + ssum[3]);

#pragma unroll
    for (int j = 0; j < NN / 256; ++j) {
        Ab[(size_t)n * NN + tid + j * 256] = f2bf(sv[j] * inv);
    }
}

// ---------------------------------------------------------------------------
// Kernel 2: x[b][n][c] fp32 -> xT[(b*64+c)][n] bf16 (K-major for GEMM1 B-op)
//                           and xN[n][(b*64+c)] bf16 (node-major for epilogue).
// grid (N/64, B), block 256.
// ---------------------------------------------------------------------------
__global__ __launch_bounds__(256) void transpose_kernel(const float* __restrict__ x,
                                                        ushort_t* __restrict__ xT,
                                                        ushort_t* __restrict__ xN) {
    const int n0 = blockIdx.x * 64;
    const int b = blockIdx.y;
    const int tid = threadIdx.x;

    __shared__ float tb[64][68];  // tb[c][nn]

#pragma unroll
    for (int l = 0; l < 4; ++l) {
        const int idx = tid + l * 256;
        const int nn = idx >> 4;
        const int c4 = (idx & 15) << 2;
        const float4 v = *(const float4*)(x + ((size_t)b * NN + n0 + nn) * CC + c4);
        tb[c4 + 0][nn] = v.x;
        tb[c4 + 1][nn] = v.y;
        tb[c4 + 2][nn] = v.z;
        tb[c4 + 3][nn] = v.w;
    }
    __syncthreads();

    // xT: row (b*64+c), contiguous in n
#pragma unroll
    for (int l = 0; l < 2; ++l) {
        const int idx = tid + l * 256;  // 512 = 64 c x 8 chunks
        const int c = idx >> 3;
        const int ch = (idx & 7) << 3;
        ushort_t pack[8];
#pragma unroll
        for (int e = 0; e < 8; ++e) pack[e] = f2bf(tb[c][ch + e]);
        *(float4*)(xT + (size_t)(b * 64 + c) * NN + n0 + ch) = *(float4*)pack;
    }
    // xN: row n, contiguous in j=(b*64+c)
#pragma unroll
    for (int l = 0; l < 2; ++l) {
        const int idx = tid + l * 256;  // 512 = 64 nn x 8 c-groups
        const int nn = idx >> 3;
        const int cg = (idx & 7) << 3;
        ushort_t pack[8];
#pragma unroll
        for (int e = 0; e < 8; ++e) pack[e] = f2bf(tb[cg + e][nn]);
        *(float4*)(xN + (size_t)(n0 + nn) * JJ + b * 64 + cg) = *(float4*)pack;
    }
}

// ---------------------------------------------------------------------------
// Kernel 3: NT-GEMM on matrix cores.
//   acc[m][j] = sum_k A[m][k]*Bt[j][k]
//   MODE 0 (pass 1): Ct[j][m] = acc (K-major, feeds pass 2)
//                    Cn[m][j] = acc (node-major, feeds epilogue)
//   MODE 1 (pass 2): Cn[m][j] = 2*acc - Zn[m][j]   (y2, node-major only)
//   128x128 tile, BK=64, 4 waves each 64x64 via 4x4 mfma_f32_16x16x32_bf16.
// ---------------------------------------------------------------------------
template <int MODE>
__global__ __launch_bounds__(256) void gemm_nt(const ushort_t* __restrict__ A,
                                               const ushort_t* __restrict__ Bt,
                                               const ushort_t* __restrict__ Zn,
                                               ushort_t* __restrict__ Ct,
                                               ushort_t* __restrict__ Cn) {
    const int j0 = blockIdx.x * 128;
    const int m0 = blockIdx.y * 128;
    const int tid = threadIdx.x;
    const int lane = tid & 63;
    const int l16 = lane & 15;
    const int quad = lane >> 4;
    const int w = tid >> 6;      // wave 0..3
    const int wm = (w >> 1) * 64;
    const int wj = (w & 1) * 64;

#define LDP 72  // padded row stride (bf16 elems)
    __shared__ ushort_t As[128 * LDP];
    __shared__ ushort_t Bs[128 * LDP];

    f32x4 acc[4][4];
#pragma unroll
    for (int mi = 0; mi < 4; ++mi)
#pragma unroll
        for (int ji = 0; ji < 4; ++ji) acc[mi][ji] = (f32x4){0.f, 0.f, 0.f, 0.f};

    for (int k0 = 0; k0 < NN; k0 += 64) {
#pragma unroll
        for (int l = 0; l < 4; ++l) {
            const int idx = tid + l * 256;
            const int row = idx >> 3;
            const int c16 = (idx & 7) << 3;
            *(float4*)&As[row * LDP + c16] =
                *(const float4*)(A + (size_t)(m0 + row) * NN + k0 + c16);
            *(float4*)&Bs[row * LDP + c16] =
                *(const float4*)(Bt + (size_t)(j0 + row) * NN + k0 + c16);
        }
        __syncthreads();

#pragma unroll
        for (int ks = 0; ks < 64; ks += 32) {
            short8 av[4], bv[4];
#pragma unroll
            for (int mi = 0; mi < 4; ++mi)
                av[mi] = *(const short8*)&As[(wm + mi * 16 + l16) * LDP + ks + quad * 8];
#pragma unroll
            for (int ji = 0; ji < 4; ++ji)
                bv[ji] = *(const short8*)&Bs[(wj + ji * 16 + l16) * LDP + ks + quad * 8];
#pragma unroll
            for (int mi = 0; mi < 4; ++mi)
#pragma unroll
                for (int ji = 0; ji < 4; ++ji)
                    acc[mi][ji] = __builtin_amdgcn_mfma_f32_16x16x32_bf16(
                        av[mi], bv[ji], acc[mi][ji], 0, 0, 0);
        }
        __syncthreads();
    }

    // C/D layout (16x16x32): col j = lane&15, row m = quad*4 + reg.
#pragma unroll
    for (int mi = 0; mi < 4; ++mi) {
#pragma unroll
        for (int ji = 0; ji < 4; ++ji) {
            const int j = j0 + wj + ji * 16 + l16;
            const int mb = m0 + wm + mi * 16 + quad * 4;
            if (MODE == 0) {
                ushort_t o[4];
#pragma unroll
                for (int r = 0; r < 4; ++r) o[r] = f2bf(acc[mi][ji][r]);
                // K-major: 4 contiguous bf16 along m
                *(unsigned long long*)(Ct + (size_t)j * NN + mb) = *(unsigned long long*)o;
                // node-major: 2B scatter (16 lanes -> 32B segments)
#pragma unroll
                for (int r = 0; r < 4; ++r) Cn[(size_t)(mb + r) * JJ + j] = o[r];
            } else {
#pragma unroll
                for (int r = 0; r < 4; ++r) {
                    const float z = bf2f(Zn[(size_t)(mb + r) * JJ + j]);
                    Cn[(size_t)(mb + r) * JJ + j] = f2bf(2.0f * acc[mi][ji][r] - z);
                }
            }
        }
    }
#undef LDP
}

// ---------------------------------------------------------------------------
// Kernel 4: fused epilogue, node-major inputs. One block per node n.
//   out[b,n,o] = bias_n[o] + sum_k sum_i srcN_k[n][(b*64+i)] * W_n[k,i,o]
// ---------------------------------------------------------------------------
__global__ __launch_bounds__(256) void out_kernel(const float* __restrict__ E,
                                                  const float* __restrict__ Wp,
                                                  const float* __restrict__ bp,
                                                  const ushort_t* __restrict__ xN,
                                                  const ushort_t* __restrict__ y1N,
                                                  const ushort_t* __restrict__ y2N,
                                                  float* __restrict__ out) {
    const int n = blockIdx.x;
    const int tid = threadIdx.x;

    __shared__ ushort_t xg[KK][BB][72];  // 27.6 KB, pad 72 -> conflict-free reads
    __shared__ float w[CC * CC];         // 16 KB
    __shared__ float en_s[ED];
    __shared__ float bias_s[CC];

    if (tid < ED) en_s[tid] = E[n * ED + tid];

    // stage all three node rows: contiguous 8 KB each, float4 loads
#pragma unroll
    for (int k = 0; k < KK; ++k) {
        const ushort_t* src = (k == 0) ? xN : (k == 1) ? y1N : y2N;
        const float4* srow = (const float4*)(src + (size_t)n * JJ);
        for (int idx = tid; idx < JJ / 8; idx += 256) {
            *(float4*)&xg[k][idx >> 3][(idx & 7) << 3] = srow[idx];
        }
    }
    __syncthreads();

    float en[ED];
#pragma unroll
    for (int d = 0; d < ED; ++d) en[d] = en_s[d];

    if (tid < CC) {
        float bsum = 0.0f;
#pragma unroll
        for (int d = 0; d < ED; ++d) bsum += en[d] * bp[d * CC + tid];
        bias_s[tid] = bsum;
    }

    const int ot4 = (tid & 15) << 2;  // o base
    const int bt = tid >> 4;          // 0..15

    float acc[4][4];
#pragma unroll
    for (int jb = 0; jb < 4; ++jb)
#pragma unroll
        for (int jo = 0; jo < 4; ++jo) acc[jb][jo] = 0.0f;

    for (int k = 0; k < KK; ++k) {
        __syncthreads();
        // synthesize W_n[k]: 1024 float4 slots, coalesced Wp reads (L2-resident)
        for (int idx = tid; idx < CC * CC / 4; idx += 256) {
            f32x4 s = (f32x4){0.f, 0.f, 0.f, 0.f};
#pragma unroll
            for (int d = 0; d < ED; ++d) {
                const float4 wv = ((const float4*)(Wp + (size_t)(d * KK + k) * CC * CC))[idx];
                s[0] += en[d] * wv.x;
                s[1] += en[d] * wv.y;
                s[2] += en[d] * wv.z;
                s[3] += en[d] * wv.w;
            }
            *(f32x4*)&w[idx << 2] = s;
        }
        __syncthreads();

#pragma unroll
        for (int i = 0; i < CC; ++i) {
            const float4 wv = *(const float4*)&w[i * CC + ot4];
            float xv[4];
#pragma unroll
            for (int jb = 0; jb < 4; ++jb) xv[jb] = bf2f(xg[k][bt + 16 * jb][i]);
#pragma unroll
            for (int jb = 0; jb < 4; ++jb) {
                acc[jb][0] += xv[jb] * wv.x;
                acc[jb][1] += xv[jb] * wv.y;
                acc[jb][2] += xv[jb] * wv.z;
                acc[jb][3] += xv[jb] * wv.w;
            }
        }
    }

#pragma unroll
    for (int jb = 0; jb < 4; ++jb) {
        const int b = bt + 16 * jb;
        float4 v;
        v.x = acc[jb][0] + bias_s[ot4 + 0];
        v.y = acc[jb][1] + bias_s[ot4 + 1];
        v.z = acc[jb][2] + bias_s[ot4 + 2];
        v.w = acc[jb][3] + bias_s[ot4 + 3];
        *(float4*)(out + ((size_t)b * NN + n) * CC + ot4) = v;
    }
}

// ---------------------------------------------------------------------------
// Host launch.
// Workspace (bf16): Ab 8.4 | xT 16.8 | xN 16.8 | y1T 16.8 | y1N 16.8 | y2N 16.8
//   = 92.4 MB.
// ---------------------------------------------------------------------------
extern "C" void kernel_launch(void* const* d_in, const int* in_sizes, int n_in,
                              void* d_out, int out_size, void* d_ws, size_t ws_size,
                              hipStream_t stream) {
    const float* x  = (const float*)d_in[0];
    const float* E  = (const float*)d_in[1];
    const float* Wp = (const float*)d_in[2];
    const float* bp = (const float*)d_in[3];

    ushort_t* Ab  = (ushort_t*)d_ws;                    // [2048][2048]
    ushort_t* xT  = Ab + (size_t)NN * NN;               // [4096][2048]
    ushort_t* xN  = xT + (size_t)JJ * NN;               // [2048][4096]
    ushort_t* y1T = xN + (size_t)NN * JJ;               // [4096][2048]
    ushort_t* y1N = y1T + (size_t)JJ * NN;              // [2048][4096]
    ushort_t* y2N = y1N + (size_t)NN * JJ;              // [2048][4096]
    float* out = (float*)d_out;

    supports_kernel<<<NN, 256, 0, stream>>>(E, Ab);
    transpose_kernel<<<dim3(NN / 64, BB), 256, 0, stream>>>(x, xT, xN);
    // y1 = A @ x : dual output (K-major + node-major)
    gemm_nt<0><<<dim3(JJ / 128, NN / 128), 256, 0, stream>>>(Ab, xT, nullptr, y1T, y1N);
    // y2 = 2 A @ y1 - x : node-major only
    gemm_nt<1><<<dim3(JJ / 128, NN / 128), 256, 0, stream>>>(Ab, y1T, xN, nullptr, y2N);
    out_kernel<<<NN, 256, 0, stream>>>(E, Wp, bp, xN, y1N, y2N, out);
}

// Round 4
// 221.528 us; speedup vs baseline: 5.6619x; 1.2255x over previous
//
#include <hip/hip_runtime.h>

// B=64, N=2048, DIM_IN=DIM_OUT=64, CHEB_K=3, EMBED_DIM=10
#define NN 2048
#define BB 64
#define CC 64
#define ED 10
#define KK 3
#define JJ (BB * CC)  // 4096

typedef unsigned short ushort_t;
typedef __attribute__((ext_vector_type(8))) short short8;   // 8 bf16 = 4 VGPRs
typedef __attribute__((ext_vector_type(4))) float f32x4;

typedef const __attribute__((address_space(1))) unsigned* gptr_t;
typedef __attribute__((address_space(3))) unsigned* lptr_t;

static __device__ __forceinline__ ushort_t f2bf(float f) {
    union { float f; unsigned u; } x{f};
    unsigned r = x.u + 0x7FFF + ((x.u >> 16) & 1);  // RTN-even
    return (ushort_t)(r >> 16);
}
static __device__ __forceinline__ float bf2f(ushort_t h) {
    union { unsigned u; float f; } x;
    x.u = ((unsigned)h) << 16;
    return x.f;
}

// ---------------------------------------------------------------------------
// Kernel 1: A_bf16[n][m] = softmax(relu(E E^T), axis=1). One block per row n.
// ---------------------------------------------------------------------------
__global__ __launch_bounds__(256) void supports_kernel(const float* __restrict__ E,
                                                       ushort_t* __restrict__ Ab) {
    const int n = blockIdx.x;
    const int tid = threadIdx.x;

    float en[ED];
#pragma unroll
    for (int d = 0; d < ED; ++d) en[d] = E[n * ED + d];

    float sv[NN / 256];
    float lmax = 0.0f;  // relu >= 0
#pragma unroll
    for (int j = 0; j < NN / 256; ++j) {
        const int m = tid + j * 256;
        const float* Em = E + m * ED;
        float dot = 0.0f;
#pragma unroll
        for (int d = 0; d < ED; ++d) dot += en[d] * Em[d];
        float s = fmaxf(dot, 0.0f);
        sv[j] = s;
        lmax = fmaxf(lmax, s);
    }

    __shared__ float smax[4];
    __shared__ float ssum[4];
#pragma unroll
    for (int off = 32; off > 0; off >>= 1) lmax = fmaxf(lmax, __shfl_down(lmax, off, 64));
    if ((tid & 63) == 0) smax[tid >> 6] = lmax;
    __syncthreads();
    const float bmax = fmaxf(fmaxf(smax[0], smax[1]), fmaxf(smax[2], smax[3]));

    float lsum = 0.0f;
#pragma unroll
    for (int j = 0; j < NN / 256; ++j) {
        sv[j] = __expf(sv[j] - bmax);
        lsum += sv[j];
    }
#pragma unroll
    for (int off = 32; off > 0; off >>= 1) lsum += __shfl_down(lsum, off, 64);
    if ((tid & 63) == 0) ssum[tid >> 6] = lsum;
    __syncthreads();
    const float inv = 1.0f / (ssum[0] + ssum[1] + ssum[2] + ssum[3]);

#pragma unroll
    for (int j = 0; j < NN / 256; ++j) {
        Ab[(size_t)n * NN + tid + j * 256] = f2bf(sv[j] * inv);
    }
}

// ---------------------------------------------------------------------------
// Kernel 2: x[b][n][c] fp32 -> xT[(b*64+c)][n] bf16 (K-major for GEMM1 B-op)
//                           and xN[n][(b*64+c)] bf16 (node-major for epilogue).
// ---------------------------------------------------------------------------
__global__ __launch_bounds__(256) void transpose_kernel(const float* __restrict__ x,
                                                        ushort_t* __restrict__ xT,
                                                        ushort_t* __restrict__ xN) {
    const int n0 = blockIdx.x * 64;
    const int b = blockIdx.y;
    const int tid = threadIdx.x;

    __shared__ float tb[64][68];  // tb[c][nn]

#pragma unroll
    for (int l = 0; l < 4; ++l) {
        const int idx = tid + l * 256;
        const int nn = idx >> 4;
        const int c4 = (idx & 15) << 2;
        const float4 v = *(const float4*)(x + ((size_t)b * NN + n0 + nn) * CC + c4);
        tb[c4 + 0][nn] = v.x;
        tb[c4 + 1][nn] = v.y;
        tb[c4 + 2][nn] = v.z;
        tb[c4 + 3][nn] = v.w;
    }
    __syncthreads();

#pragma unroll
    for (int l = 0; l < 2; ++l) {
        const int idx = tid + l * 256;
        const int c = idx >> 3;
        const int ch = (idx & 7) << 3;
        ushort_t pack[8];
#pragma unroll
        for (int e = 0; e < 8; ++e) pack[e] = f2bf(tb[c][ch + e]);
        *(float4*)(xT + (size_t)(b * 64 + c) * NN + n0 + ch) = *(float4*)pack;
    }
#pragma unroll
    for (int l = 0; l < 2; ++l) {
        const int idx = tid + l * 256;
        const int nn = idx >> 3;
        const int cg = (idx & 7) << 3;
        ushort_t pack[8];
#pragma unroll
        for (int e = 0; e < 8; ++e) pack[e] = f2bf(tb[cg + e][nn]);
        *(float4*)(xN + (size_t)(n0 + nn) * JJ + b * 64 + cg) = *(float4*)pack;
    }
}

// ---------------------------------------------------------------------------
// Kernel 2b (one-time prep): Wp[d][k][i][o] fp32 -> WpT[(d*3+k)][o][i] bf16.
// 30 blocks, 64x64 transpose each.
// ---------------------------------------------------------------------------
__global__ __launch_bounds__(256) void wprep_kernel(const float* __restrict__ Wp,
                                                    ushort_t* __restrict__ WpT) {
    const int dk = blockIdx.x;
    const int tid = threadIdx.x;
    const float* src = Wp + (size_t)dk * CC * CC;

    __shared__ float tb[64][68];  // tb[o][i]

#pragma unroll
    for (int l = 0; l < 4; ++l) {
        const int idx = tid + l * 256;
        const int i = idx >> 4;
        const int o4 = (idx & 15) << 2;
        const float4 v = *(const float4*)(src + i * CC + o4);
        tb[o4 + 0][i] = v.x;
        tb[o4 + 1][i] = v.y;
        tb[o4 + 2][i] = v.z;
        tb[o4 + 3][i] = v.w;
    }
    __syncthreads();

#pragma unroll
    for (int l = 0; l < 2; ++l) {
        const int idx = tid + l * 256;
        const int o = idx >> 3;
        const int ic = (idx & 7) << 3;
        ushort_t pack[8];
#pragma unroll
        for (int e = 0; e < 8; ++e) pack[e] = f2bf(tb[o][ic + e]);
        *(float4*)(WpT + (size_t)dk * CC * CC + o * CC + ic) = *(float4*)pack;
    }
}

// ---------------------------------------------------------------------------
// Kernel 3: NT-GEMM on matrix cores, global_load_lds(16B) staging with XOR
// swizzle (chunk ^= row&7 on the GLOBAL side; LDS tile is unpadded [128][64]).
//   acc[m][j] = sum_k A[m][k]*Bt[j][k]
//   MODE 0: Ct[j][m] = acc (K-major) and Cn[m][j] = acc (node-major)
//   MODE 1: Cn[m][j] = 2*acc - Zn[m][j]
// ---------------------------------------------------------------------------
template <int MODE>
__global__ __launch_bounds__(256) void gemm_nt(const ushort_t* __restrict__ A,
                                               const ushort_t* __restrict__ Bt,
                                               const ushort_t* __restrict__ Zn,
                                               ushort_t* __restrict__ Ct,
                                               ushort_t* __restrict__ Cn) {
    const int j0 = blockIdx.x * 128;
    const int m0 = blockIdx.y * 128;
    const int tid = threadIdx.x;
    const int lane = tid & 63;
    const int l16 = lane & 15;
    const int quad = lane >> 4;
    const int w = tid >> 6;      // wave 0..3
    const int wm = (w >> 1) * 64;
    const int wj = (w & 1) * 64;
    const int lr = lane >> 3;    // staging: row-in-group 0..7
    const int lc = lane & 7;     // staging: chunk 0..7
    const int swz = lc ^ lr;     // global chunk to fetch for this LDS slot

    __shared__ ushort_t As[128 * 64];  // 16 KB, unpadded; slot(r,c) holds chunk c^(r&7)
    __shared__ ushort_t Bs[128 * 64];

    f32x4 acc[4][4];
#pragma unroll
    for (int mi = 0; mi < 4; ++mi)
#pragma unroll
        for (int ji = 0; ji < 4; ++ji) acc[mi][ji] = (f32x4){0.f, 0.f, 0.f, 0.f};

    for (int k0 = 0; k0 < NN; k0 += 64) {
        // each wave stages 32 rows of A and 32 rows of B: 4 insts x (8 rows x 8 chunks)
#pragma unroll
        for (int inst = 0; inst < 4; ++inst) {
            const int rbase = w * 32 + inst * 8;
            const int row = rbase + lr;
            __builtin_amdgcn_global_load_lds(
                (gptr_t)(A + (size_t)(m0 + row) * NN + k0 + swz * 8),
                (lptr_t)&As[rbase * 64], 16, 0, 0);
            __builtin_amdgcn_global_load_lds(
                (gptr_t)(Bt + (size_t)(j0 + row) * NN + k0 + swz * 8),
                (lptr_t)&Bs[rbase * 64], 16, 0, 0);
        }
        __syncthreads();

#pragma unroll
        for (int ks = 0; ks < 64; ks += 32) {
            const int qb = (ks >> 3) + quad;
            short8 av[4], bv[4];
#pragma unroll
            for (int mi = 0; mi < 4; ++mi) {
                const int rA = wm + mi * 16 + l16;
                av[mi] = *(const short8*)&As[rA * 64 + ((qb ^ (rA & 7)) << 3)];
            }
#pragma unroll
            for (int ji = 0; ji < 4; ++ji) {
                const int rB = wj + ji * 16 + l16;
                bv[ji] = *(const short8*)&Bs[rB * 64 + ((qb ^ (rB & 7)) << 3)];
            }
#pragma unroll
            for (int mi = 0; mi < 4; ++mi)
#pragma unroll
                for (int ji = 0; ji < 4; ++ji)
                    acc[mi][ji] = __builtin_amdgcn_mfma_f32_16x16x32_bf16(
                        av[mi], bv[ji], acc[mi][ji], 0, 0, 0);
        }
        __syncthreads();
    }

    // C/D layout (16x16x32): col j = lane&15, row m = quad*4 + reg.
#pragma unroll
    for (int mi = 0; mi < 4; ++mi) {
#pragma unroll
        for (int ji = 0; ji < 4; ++ji) {
            const int j = j0 + wj + ji * 16 + l16;
            const int mb = m0 + wm + mi * 16 + quad * 4;
            if (MODE == 0) {
                ushort_t o[4];
#pragma unroll
                for (int r = 0; r < 4; ++r) o[r] = f2bf(acc[mi][ji][r]);
                *(unsigned long long*)(Ct + (size_t)j * NN + mb) = *(unsigned long long*)o;
#pragma unroll
                for (int r = 0; r < 4; ++r) Cn[(size_t)(mb + r) * JJ + j] = o[r];
            } else {
#pragma unroll
                for (int r = 0; r < 4; ++r) {
                    const float z = bf2f(Zn[(size_t)(mb + r) * JJ + j]);
                    Cn[(size_t)(mb + r) * JJ + j] = f2bf(2.0f * acc[mi][ji][r] - z);
                }
            }
        }
    }
}

// ---------------------------------------------------------------------------
// Kernel 4: MFMA epilogue. One block per node n.
//   Per node: GEMM [B=64 x KI=192] @ [KI=192 x O=64] via mfma_f32_16x16x32_bf16.
//   X rows staged from node-major xN/y1N/y2N; W_n synthesized in bf16 from
//   WpT[(d,k)][o][i] into B-fragment layout Wt[o][ki].
// ---------------------------------------------------------------------------
#define XLD 200  // LDS row stride (bf16 elems) for xg/Wt: 400 B -> 2-way banks
__global__ __launch_bounds__(256) void out_kernel(const float* __restrict__ E,
                                                  const ushort_t* __restrict__ WpT,
                                                  const float* __restrict__ bp,
                                                  const ushort_t* __restrict__ xN,
                                                  const ushort_t* __restrict__ y1N,
                                                  const ushort_t* __restrict__ y2N,
                                                  float* __restrict__ out) {
    const int n = blockIdx.x;
    const int tid = threadIdx.x;

    __shared__ ushort_t xg[BB * XLD];  // 25.6 KB: xg[b][k*64+i]
    __shared__ ushort_t Wt[CC * XLD];  // 25.6 KB: Wt[o][k*64+i]
    __shared__ float en_s[ED];
    __shared__ float bias_s[CC];

    if (tid < ED) en_s[tid] = E[n * ED + tid];
    __syncthreads();

    float en[ED];
#pragma unroll
    for (int d = 0; d < ED; ++d) en[d] = en_s[d];

    if (tid < CC) {
        float bsum = 0.0f;
#pragma unroll
        for (int d = 0; d < ED; ++d) bsum += en[d] * bp[d * CC + tid];
        bias_s[tid] = bsum;
    }

    // stage X rows: 3 sources x 512 chunks of 8 bf16 (contiguous 8 KB each)
#pragma unroll
    for (int k = 0; k < KK; ++k) {
        const ushort_t* src = (k == 0) ? xN : (k == 1) ? y1N : y2N;
        const float4* srow = (const float4*)(src + (size_t)n * JJ);
        for (int idx = tid; idx < JJ / 8; idx += 256) {
            *(float4*)&xg[(idx >> 3) * XLD + k * 64 + ((idx & 7) << 3)] = srow[idx];
        }
    }

    // synthesize Wt[o][ki] bf16: 1536 chunks of 8, fp32 accumulate over d
    for (int t = tid; t < CC * 24; t += 256) {
        const int o = t / 24;
        const int kc = t % 24;
        const int k = kc >> 3;
        const int ic = (kc & 7) << 3;
        float s[8];
#pragma unroll
        for (int e = 0; e < 8; ++e) s[e] = 0.0f;
#pragma unroll
        for (int d = 0; d < ED; ++d) {
            const float4 wv4 = *(const float4*)(WpT + ((size_t)(d * KK + k) * CC + o) * CC + ic);
            const ushort_t* wp = (const ushort_t*)&wv4;
#pragma unroll
            for (int e = 0; e < 8; ++e) s[e] += en[d] * bf2f(wp[e]);
        }
        ushort_t pack[8];
#pragma unroll
        for (int e = 0; e < 8; ++e) pack[e] = f2bf(s[e]);
        *(float4*)&Wt[o * XLD + k * 64 + ic] = *(float4*)pack;
    }
    __syncthreads();

    const int lane = tid & 63;
    const int l16 = lane & 15;
    const int quad = lane >> 4;
    const int bm = (tid >> 6) * 16;  // wave's 16 b-rows

    f32x4 acc[4];
#pragma unroll
    for (int ji = 0; ji < 4; ++ji) acc[ji] = (f32x4){0.f, 0.f, 0.f, 0.f};

#pragma unroll
    for (int kc = 0; kc < 6; ++kc) {  // K = 192 = 6 x 32
        const short8 av = *(const short8*)&xg[(bm + l16) * XLD + kc * 32 + quad * 8];
#pragma unroll
        for (int ji = 0; ji < 4; ++ji) {
            const short8 bv = *(const short8*)&Wt[(ji * 16 + l16) * XLD + kc * 32 + quad * 8];
            acc[ji] = __builtin_amdgcn_mfma_f32_16x16x32_bf16(av, bv, acc[ji], 0, 0, 0);
        }
    }

    // C/D: col o = l16 (+16*ji), row b = bm + quad*4 + r. 16-lane rows -> 64 B stores.
#pragma unroll
    for (int ji = 0; ji < 4; ++ji) {
        const int o = ji * 16 + l16;
        const float bo = bias_s[o];
#pragma unroll
        for (int r = 0; r < 4; ++r) {
            const int b = bm + quad * 4 + r;
            out[((size_t)b * NN + n) * CC + o] = acc[ji][r] + bo;
        }
    }
}
#undef XLD

// ---------------------------------------------------------------------------
// Host launch.
// Workspace (bf16): Ab 8 | xT 16 | xN 16 | y1T 16 | y1N 16 | y2N 16 | WpT 0.24
//   = 88.2 MiB.
// ---------------------------------------------------------------------------
extern "C" void kernel_launch(void* const* d_in, const int* in_sizes, int n_in,
                              void* d_out, int out_size, void* d_ws, size_t ws_size,
                              hipStream_t stream) {
    const float* x  = (const float*)d_in[0];
    const float* E  = (const float*)d_in[1];
    const float* Wp = (const float*)d_in[2];
    const float* bp = (const float*)d_in[3];

    ushort_t* Ab  = (ushort_t*)d_ws;                    // [2048][2048]
    ushort_t* xT  = Ab + (size_t)NN * NN;               // [4096][2048]
    ushort_t* xN  = xT + (size_t)JJ * NN;               // [2048][4096]
    ushort_t* y1T = xN + (size_t)NN * JJ;               // [4096][2048]
    ushort_t* y1N = y1T + (size_t)JJ * NN;              // [2048][4096]
    ushort_t* y2N = y1N + (size_t)NN * JJ;              // [2048][4096]
    ushort_t* WpT = y2N + (size_t)NN * JJ;              // [30][64][64]
    float* out = (float*)d_out;

    supports_kernel<<<NN, 256, 0, stream>>>(E, Ab);
    transpose_kernel<<<dim3(NN / 64, BB), 256, 0, stream>>>(x, xT, xN);
    wprep_kernel<<<ED * KK, 256, 0, stream>>>(Wp, WpT);
    // y1 = A @ x : dual output (K-major + node-major)
    gemm_nt<0><<<dim3(JJ / 128, NN / 128), 256, 0, stream>>>(Ab, xT, nullptr, y1T, y1N);
    // y2 = 2 A @ y1 - x : node-major only
    gemm_nt<1><<<dim3(JJ / 128, NN / 128), 256, 0, stream>>>(Ab, y1T, xN, nullptr, y2N);
    out_kernel<<<NN, 256, 0, stream>>>(E, WpT, bp, xN, y1N, y2N, out);
}